// Round 17
// baseline (262.252 us; speedup 1.0000x reference)
//
#include <hip/hip_runtime.h>
#include <hip/hip_bf16.h>

#define B_ 128
#define T_ 512
#define L_ 256

typedef float f32x4 __attribute__((ext_vector_type(4)));
typedef unsigned uint32x4 __attribute__((ext_vector_type(4)));

__device__ __forceinline__ unsigned short f2bf(float x) {  // RNE f32->bf16
    unsigned u = __builtin_bit_cast(unsigned, x);
    return (unsigned short)((u + 0x7fff + ((u >> 16) & 1)) >> 16);
}

// Physical-AGPR staging (round-9/10-proven; regalloc cannot touch).
#define AW(n, v) asm volatile("v_accvgpr_write_b32 a" #n ", %0" :: "v"(v) : "a" #n)
#define STGF(F, A0, A1, A2, A3) { uint32x4 qq = etb4[vbase + F * 64]; \
    AW(A0, qq[0]); AW(A1, qq[1]); AW(A2, qq[2]); AW(A3, qq[3]); }

// MFMA with B operand in hard-coded physical AGPRs (gfx950 unified RF).
#define MFMA_AB(ACC, AF, LO, HI) \
    asm volatile("v_mfma_f32_16x16x32_bf16 %0, %1, a[" #LO ":" #HI "], %0" \
                 : "+v"(ACC) : "v"(AF))

// lgkmcnt-only barrier (no vmcnt drain).
#define BARRIER() asm volatile("s_waitcnt lgkmcnt(0)\n\ts_barrier" ::: "memory")

// ---------------------------------------------------------------------------
// Kernel A: ETB = bf16(exp(trans)) pre-packed in MFMA B-fragment order.
// (unchanged — HW-verified by round-10 absmax 0.0)
// ---------------------------------------------------------------------------
__global__ __launch_bounds__(256) void k_exptrans(const float* __restrict__ trans,
                                                  unsigned short* __restrict__ ETB) {
    int l = blockIdx.x;          // 256 blocks = rows of trans
    int m = threadIdx.x;         // 256 threads = cols
    unsigned short v = f2bf(__expf(trans[l * L_ + m]));
    unsigned byte = (unsigned)((m >> 4) * 8 + (l >> 5)) * 1024u
                  + (unsigned)(((l >> 3) & 3) * 16 + (m & 15)) * 16u
                  + (unsigned)(((l >> 1) & 3)) * 4u + (unsigned)(l & 1) * 2u;
    *(unsigned short*)((char*)ETB + byte) = v;
}

// ---------------------------------------------------------------------------
// Kernel B: labels from one-hot y_true (one wave per row)
// ---------------------------------------------------------------------------
__global__ __launch_bounds__(256) void k_labels(const float* __restrict__ y_true,
                                                int* __restrict__ labels) {
    int wid = threadIdx.x >> 6, lane = threadIdx.x & 63;
    int r = blockIdx.x * 4 + wid;
    const float4* row = (const float4*)(y_true + (size_t)r * L_);
    float4 v = row[lane];
    int loc = -1;
    if (v.x > 0.5f) loc = lane * 4 + 0;
    if (v.y > 0.5f) loc = lane * 4 + 1;
    if (v.z > 0.5f) loc = lane * 4 + 2;
    if (v.w > 0.5f) loc = lane * 4 + 3;
    unsigned long long m = __ballot(loc >= 0);
    int src = __ffsll(m) - 1;
    int lab = __shfl(loc, src, 64);
    if (lane == 0) labels[r] = lab;
}

// ---------------------------------------------------------------------------
// Kernel C: path_score
// ---------------------------------------------------------------------------
__global__ __launch_bounds__(256) void k_path(const float* __restrict__ y_pre,
                                              const float* __restrict__ trans,
                                              const int* __restrict__ labels,
                                              float* __restrict__ path) {
    int b = blockIdx.x, tid = threadIdx.x;
    const int* lb = labels + b * T_;
    float acc = 0.f;
    for (int t = tid; t < T_; t += 256) {
        int l1 = lb[t];
        acc += y_pre[((size_t)b * T_ + t) * L_ + l1];
        if (t + 1 < T_) acc += trans[l1 * L_ + lb[t + 1]];
    }
#pragma unroll
    for (int off = 1; off < 64; off <<= 1) acc += __shfl_xor(acc, off, 64);
    __shared__ float red[4];
    int wid = tid >> 6, lane = tid & 63;
    if (lane == 0) red[wid] = acc;
    __syncthreads();
    if (tid == 0) path[b] = red[0] + red[1] + red[2] + red[3];
}

// ---------------------------------------------------------------------------
// Kernel D: forward recursion via MFMA — round-15 structure (4-acc MFMA32),
// with the LOG + nmr-WRITE DEFERRED one phase. Diagnosis: per-SIMD MFMA
// issue rate is ~16cy/inst => 32 MFMAs = 512cy pipe floor; the other ~570cy
// is serial latency, and the log was ON the barrier path via lane0's nmr
// ds_write (must retire before lgkmcnt(0)). nmr has lag 2, so the write only
// needs the NEXT barrier: compute s_{t-1} (log) + write at phase t top,
// overlapping the af-read latency. Pre-barrier tail = select+mul+cvt+write.
// Ring: phase t writes s_{t-1} -> slot (t-1)&3, reads D_t = slot (t-2)&3.
// ---------------------------------------------------------------------------
#define MFMA32()                                                         \
        MFMA_AB(c0, af0,   0,   3); MFMA_AB(c1, af0,  32,  35);          \
        MFMA_AB(c2, af0,  64,  67); MFMA_AB(c3, af0,  96,  99);          \
        MFMA_AB(c0, af1,   4,   7); MFMA_AB(c1, af1,  36,  39);          \
        MFMA_AB(c2, af1,  68,  71); MFMA_AB(c3, af1, 100, 103);          \
        MFMA_AB(c0, af2,   8,  11); MFMA_AB(c1, af2,  40,  43);          \
        MFMA_AB(c2, af2,  72,  75); MFMA_AB(c3, af2, 104, 107);          \
        MFMA_AB(c0, af3,  12,  15); MFMA_AB(c1, af3,  44,  47);          \
        MFMA_AB(c2, af3,  76,  79); MFMA_AB(c3, af3, 108, 111);          \
        MFMA_AB(c0, af4,  16,  19); MFMA_AB(c1, af4,  48,  51);          \
        MFMA_AB(c2, af4,  80,  83); MFMA_AB(c3, af4, 112, 115);          \
        MFMA_AB(c0, af5,  20,  23); MFMA_AB(c1, af5,  52,  55);          \
        MFMA_AB(c2, af5,  84,  87); MFMA_AB(c3, af5, 116, 119);          \
        MFMA_AB(c0, af6,  24,  27); MFMA_AB(c1, af6,  56,  59);          \
        MFMA_AB(c2, af6,  88,  91); MFMA_AB(c3, af6, 120, 123);          \
        MFMA_AB(c0, af7,  28,  31); MFMA_AB(c1, af7,  60,  63);          \
        MFMA_AB(c2, af7,  92,  95); MFMA_AB(c3, af7, 124, 127);

#define STEP(TT, PH_RD, PH_WR, DS_R, DS_W, EREG)                         \
    {                                                                    \
        float Dt = nmr[DS_R];               /* s_{t-2}[0], lag-2 slot */ \
        const uint32x4* pA = (const uint32x4*)ph[PH_RD];                 \
        uint32x4 af0 = pA[g];      uint32x4 af1 = pA[g + 4];             \
        uint32x4 af2 = pA[g + 8];  uint32x4 af3 = pA[g + 12];            \
        uint32x4 af4 = pA[g + 16]; uint32x4 af5 = pA[g + 20];            \
        uint32x4 af6 = pA[g + 24]; uint32x4 af7 = pA[g + 28];            \
        /* deferred from previous phase — overlaps af-read latency: */   \
        s = NP_sav + __logf(val_prev) + e_sav;                           \
        if (tid == 0) nmr[DS_W] = s;        /* s_{t-1} -> slot (t-1)&3 */\
        float scale = __expf(NPprev + EREG - Dt);  /* overlaps MFMA */   \
        f32x4 c0 = {0.f,0.f,0.f,0.f}, c1 = {0.f,0.f,0.f,0.f};            \
        f32x4 c2 = {0.f,0.f,0.f,0.f}, c3 = {0.f,0.f,0.f,0.f};            \
        MFMA32()                                                         \
        float val = (g < 2) ? ((g == 0) ? c0[0] : c1[0])                 \
                            : ((g == 2) ? c2[0] : c3[0]);                \
        ph[PH_WR][st] = f2bf(val * scale);   /* only this pre-barrier */ \
        NP_sav = NPprev; val_prev = val; e_sav = EREG;                   \
        NPprev = Dt;                                                     \
        { int tp = (TT) + 4; if (tp > T_ - 1) tp = T_ - 1;               \
          EREG = yp[(size_t)tp * L_ + st]; } /* reload, distance 4 */    \
        BARRIER();                                                       \
    }

__global__ void __launch_bounds__(256, 1)
k_forward(const float* __restrict__ yp_all,
          const unsigned short* __restrict__ ETB,
          const float* __restrict__ path,
          float* __restrict__ out) {
    int b = blockIdx.x, tid = threadIdx.x;
    int w = tid >> 6;            // wave: owns states [64w, 64w+64)
    int i = tid & 63;            // lane
    int g = i >> 4;              // lane group 0..3
    const int st = (w << 6) + i; // this lane's state
    const float* yp = yp_all + (size_t)b * T_ * L_;

    // ---- stage B-fragments (32 x 16B) into physical a0..a127 ----
    {
        const uint32x4* etb4 = (const uint32x4*)ETB;
        int vbase = w * 2048 + i;
        STGF( 0,   0,  1,  2,  3)  STGF( 1,   4,  5,  6,  7)
        STGF( 2,   8,  9, 10, 11)  STGF( 3,  12, 13, 14, 15)
        STGF( 4,  16, 17, 18, 19)  STGF( 5,  20, 21, 22, 23)
        STGF( 6,  24, 25, 26, 27)  STGF( 7,  28, 29, 30, 31)
        STGF( 8,  32, 33, 34, 35)  STGF( 9,  36, 37, 38, 39)
        STGF(10,  40, 41, 42, 43)  STGF(11,  44, 45, 46, 47)
        STGF(12,  48, 49, 50, 51)  STGF(13,  52, 53, 54, 55)
        STGF(14,  56, 57, 58, 59)  STGF(15,  60, 61, 62, 63)
        STGF(16,  64, 65, 66, 67)  STGF(17,  68, 69, 70, 71)
        STGF(18,  72, 73, 74, 75)  STGF(19,  76, 77, 78, 79)
        STGF(20,  80, 81, 82, 83)  STGF(21,  84, 85, 86, 87)
        STGF(22,  88, 89, 90, 91)  STGF(23,  92, 93, 94, 95)
        STGF(24,  96, 97, 98, 99)  STGF(25, 100,101,102,103)
        STGF(26, 104,105,106,107)  STGF(27, 108,109,110,111)
        STGF(28, 112,113,114,115)  STGF(29, 116,117,118,119)
        STGF(30, 120,121,122,123)  STGF(31, 124,125,126,127)
    }

    __shared__ alignas(16) unsigned short ph[2][L_];  // p (bf16), dbuf
    __shared__ float red[8];
    __shared__ float nmr[4];                          // D ring, lag-2

    // ---- init: s0, exact max N0, p0; seed deferred-log state ----
    float s = yp[st];
    {
        float v = s;
#pragma unroll
        for (int off = 1; off < 64; off <<= 1) v = fmaxf(v, __shfl_xor(v, off, 64));
        if (i == 0) red[w] = v;
        __syncthreads();
        if (tid == 0) {
            float M = fmaxf(fmaxf(red[0], red[1]), fmaxf(red[2], red[3]));
            nmr[0] = M; nmr[1] = M; nmr[2] = M; nmr[3] = M;
        }
        __syncthreads();
    }
    float NPprev = nmr[0];                 // D_0 = N0
    float v0 = __expf(s - NPprev);
    ph[1][st] = f2bf(v0);                  // p_0
    // seed deferred state so phase 1 reconstructs s_0 = M + log(v0) + 0:
    float val_prev = v0, e_sav = 0.f, NP_sav = NPprev;

    // emit regs: e0=E(1), e1=E(2), e2=E(3), e3=E(4)
    float e0 = yp[(size_t)1 * L_ + st];
    float e1 = yp[(size_t)2 * L_ + st];
    float e2 = yp[(size_t)3 * L_ + st];
    float e3 = yp[(size_t)4 * L_ + st];
    __syncthreads();   // p0 + nmr visible (one-time full drain is fine)

    // main loop: t = 1..508 in 4x bodies (t ≡ 1 mod 4)
    // positions: t≡1: DS_R=3 DS_W=0 | t≡2: 0,1 | t≡3: 1,2 | t≡0: 2,3
    for (int t = 1; t < 509; t += 4) {
        STEP(t + 0, 1, 0, 3, 0, e0)
        STEP(t + 1, 0, 1, 0, 1, e1)
        STEP(t + 2, 1, 0, 1, 2, e2)
        STEP(t + 3, 0, 1, 2, 3, e3)
    }
    // peeled: t = 509, 510, 511
    STEP(509, 1, 0, 3, 0, e0)
    STEP(510, 0, 1, 0, 1, e1)
    STEP(511, 1, 0, 1, 2, e2)

    // final deferred: s_511
    s = NP_sav + __logf(val_prev) + e_sav;

    // ---- final logsumexp over states (all lanes hold unique st) ----
    {
        float v = s;
#pragma unroll
        for (int off = 1; off < 64; off <<= 1) v = fmaxf(v, __shfl_xor(v, off, 64));
        if (i == 0) red[w] = v;
    }
    __syncthreads();
    float M = fmaxf(fmaxf(red[0], red[1]), fmaxf(red[2], red[3]));
    float e = __expf(s - M);
#pragma unroll
    for (int off = 1; off < 64; off <<= 1) e += __shfl_xor(e, off, 64);
    if (i == 0) red[4 + w] = e;
    __syncthreads();
    if (tid == 0)
        out[b] = M + __logf((red[4] + red[5]) + (red[6] + red[7])) - path[b];
}

// ---------------------------------------------------------------------------
extern "C" void kernel_launch(void* const* d_in, const int* in_sizes, int n_in,
                              void* d_out, int out_size, void* d_ws, size_t ws_size,
                              hipStream_t stream) {
    const float* y_true = (const float*)d_in[0];
    const float* y_pre  = (const float*)d_in[1];
    const float* trans  = (const float*)d_in[2];
    float* out = (float*)d_out;

    char* ws = (char*)d_ws;
    unsigned short* ETB = (unsigned short*)ws;            // 128 KiB (frag order)
    int* labels = (int*)(ws + 131072);                    // 256 KiB
    float* path = (float*)(ws + 131072 + 262144);         // 512 B

    hipLaunchKernelGGL(k_exptrans, dim3(L_), dim3(L_), 0, stream, trans, ETB);
    hipLaunchKernelGGL(k_labels, dim3(B_ * T_ / 4), dim3(256), 0, stream, y_true, labels);
    hipLaunchKernelGGL(k_path, dim3(B_), dim3(256), 0, stream, y_pre, trans, labels, path);
    hipLaunchKernelGGL(k_forward, dim3(B_), dim3(256), 0, stream, y_pre, ETB, path, out);
}

// Round 18
// 239.504 us; speedup vs baseline: 1.0950x; 1.0950x over previous
//
#include <hip/hip_runtime.h>
#include <hip/hip_bf16.h>

#define B_ 128
#define T_ 512
#define L_ 256

typedef float f32x4 __attribute__((ext_vector_type(4)));
typedef unsigned uint32x4 __attribute__((ext_vector_type(4)));

__device__ __forceinline__ unsigned short f2bf(float x) {  // RNE f32->bf16
    unsigned u = __builtin_bit_cast(unsigned, x);
    return (unsigned short)((u + 0x7fff + ((u >> 16) & 1)) >> 16);
}

// Physical-AGPR staging (round-9/10-proven; regalloc cannot touch).
#define AW(n, v) asm volatile("v_accvgpr_write_b32 a" #n ", %0" :: "v"(v) : "a" #n)
#define STGF(F, A0, A1, A2, A3) { uint32x4 qq = etb4[vbase + F * 64]; \
    AW(A0, qq[0]); AW(A1, qq[1]); AW(A2, qq[2]); AW(A3, qq[3]); }

// MFMA with B operand in hard-coded physical AGPRs (gfx950 unified RF).
#define MFMA_AB(ACC, AF, LO, HI) \
    asm volatile("v_mfma_f32_16x16x32_bf16 %0, %1, a[" #LO ":" #HI "], %0" \
                 : "+v"(ACC) : "v"(AF))

// lgkmcnt-only barrier. NOTE: the "memory" clobber may still make the
// backend drain vmcnt here (conservatism) — which is exactly why the emit
// reload is hoisted to the step TOP this round (exposure ~100cy not ~500).
#define BARRIER() asm volatile("s_waitcnt lgkmcnt(0)\n\ts_barrier" ::: "memory")

// ---------------------------------------------------------------------------
// Kernel A: ETB = bf16(exp(trans)) pre-packed in MFMA B-fragment order.
// (unchanged — HW-verified by round-10 absmax 0.0)
// ---------------------------------------------------------------------------
__global__ __launch_bounds__(256) void k_exptrans(const float* __restrict__ trans,
                                                  unsigned short* __restrict__ ETB) {
    int l = blockIdx.x;          // 256 blocks = rows of trans
    int m = threadIdx.x;         // 256 threads = cols
    unsigned short v = f2bf(__expf(trans[l * L_ + m]));
    unsigned byte = (unsigned)((m >> 4) * 8 + (l >> 5)) * 1024u
                  + (unsigned)(((l >> 3) & 3) * 16 + (m & 15)) * 16u
                  + (unsigned)(((l >> 1) & 3)) * 4u + (unsigned)(l & 1) * 2u;
    *(unsigned short*)((char*)ETB + byte) = v;
}

// ---------------------------------------------------------------------------
// Kernel B: labels from one-hot y_true (one wave per row)
// ---------------------------------------------------------------------------
__global__ __launch_bounds__(256) void k_labels(const float* __restrict__ y_true,
                                                int* __restrict__ labels) {
    int wid = threadIdx.x >> 6, lane = threadIdx.x & 63;
    int r = blockIdx.x * 4 + wid;
    const float4* row = (const float4*)(y_true + (size_t)r * L_);
    float4 v = row[lane];
    int loc = -1;
    if (v.x > 0.5f) loc = lane * 4 + 0;
    if (v.y > 0.5f) loc = lane * 4 + 1;
    if (v.z > 0.5f) loc = lane * 4 + 2;
    if (v.w > 0.5f) loc = lane * 4 + 3;
    unsigned long long m = __ballot(loc >= 0);
    int src = __ffsll(m) - 1;
    int lab = __shfl(loc, src, 64);
    if (lane == 0) labels[r] = lab;
}

// ---------------------------------------------------------------------------
// Kernel C: path_score
// ---------------------------------------------------------------------------
__global__ __launch_bounds__(256) void k_path(const float* __restrict__ y_pre,
                                              const float* __restrict__ trans,
                                              const int* __restrict__ labels,
                                              float* __restrict__ path) {
    int b = blockIdx.x, tid = threadIdx.x;
    const int* lb = labels + b * T_;
    float acc = 0.f;
    for (int t = tid; t < T_; t += 256) {
        int l1 = lb[t];
        acc += y_pre[((size_t)b * T_ + t) * L_ + l1];
        if (t + 1 < T_) acc += trans[l1 * L_ + lb[t + 1]];
    }
#pragma unroll
    for (int off = 1; off < 64; off <<= 1) acc += __shfl_xor(acc, off, 64);
    __shared__ float red[4];
    int wid = tid >> 6, lane = tid & 63;
    if (lane == 0) red[wid] = acc;
    __syncthreads();
    if (tid == 0) path[b] = red[0] + red[1] + red[2] + red[3];
}

// ---------------------------------------------------------------------------
// Kernel D: forward recursion via MFMA — round-15 structure verbatim (best,
// 229us), with ONE change: the emit reload is issued at the STEP TOP (old
// value saved to e_cur first). Theory: every barrier drains vmcnt (memory
// clobber conservatism — why the r15 asm-barrier swap was a no-op), so a
// tail-issued load exposes its full HBM latency (~500cy = the unexplained
// step residual). Top-issue gives the load ~800cy of step body to complete.
// ---------------------------------------------------------------------------
#define MFMA32()                                                         \
        MFMA_AB(c0, af0,   0,   3); MFMA_AB(c1, af0,  32,  35);          \
        MFMA_AB(c2, af0,  64,  67); MFMA_AB(c3, af0,  96,  99);          \
        MFMA_AB(c0, af1,   4,   7); MFMA_AB(c1, af1,  36,  39);          \
        MFMA_AB(c2, af1,  68,  71); MFMA_AB(c3, af1, 100, 103);          \
        MFMA_AB(c0, af2,   8,  11); MFMA_AB(c1, af2,  40,  43);          \
        MFMA_AB(c2, af2,  72,  75); MFMA_AB(c3, af2, 104, 107);          \
        MFMA_AB(c0, af3,  12,  15); MFMA_AB(c1, af3,  44,  47);          \
        MFMA_AB(c2, af3,  76,  79); MFMA_AB(c3, af3, 108, 111);          \
        MFMA_AB(c0, af4,  16,  19); MFMA_AB(c1, af4,  48,  51);          \
        MFMA_AB(c2, af4,  80,  83); MFMA_AB(c3, af4, 112, 115);          \
        MFMA_AB(c0, af5,  20,  23); MFMA_AB(c1, af5,  52,  55);          \
        MFMA_AB(c2, af5,  84,  87); MFMA_AB(c3, af5, 116, 119);          \
        MFMA_AB(c0, af6,  24,  27); MFMA_AB(c1, af6,  56,  59);          \
        MFMA_AB(c2, af6,  88,  91); MFMA_AB(c3, af6, 120, 123);          \
        MFMA_AB(c0, af7,  28,  31); MFMA_AB(c1, af7,  60,  63);          \
        MFMA_AB(c2, af7,  92,  95); MFMA_AB(c3, af7, 124, 127);

#define STEP(TT, PH_RD, PH_WR, DSLOT, WSLOT, EREG)                       \
    {                                                                    \
        float e_cur = EREG;                  /* E(t), 4-step-old load */ \
        { int tp = (TT) + 4; if (tp > T_ - 1) tp = T_ - 1;               \
          EREG = yp[(size_t)tp * L_ + st]; } /* issue E(t+4) at TOP */   \
        float Dt = nmr[DSLOT];              /* s_{t-2}[0], 2 barriers old */ \
        float scale = __expf(NPprev + e_cur - Dt);  /* overlaps MFMA */  \
        const uint32x4* pA = (const uint32x4*)ph[PH_RD];                 \
        uint32x4 af0 = pA[g];      uint32x4 af1 = pA[g + 4];             \
        uint32x4 af2 = pA[g + 8];  uint32x4 af3 = pA[g + 12];            \
        uint32x4 af4 = pA[g + 16]; uint32x4 af5 = pA[g + 20];            \
        uint32x4 af6 = pA[g + 24]; uint32x4 af7 = pA[g + 28];            \
        f32x4 c0 = {0.f,0.f,0.f,0.f}, c1 = {0.f,0.f,0.f,0.f};            \
        f32x4 c2 = {0.f,0.f,0.f,0.f}, c3 = {0.f,0.f,0.f,0.f};            \
        MFMA32()                                                         \
        float val = (g < 2) ? ((g == 0) ? c0[0] : c1[0])                 \
                            : ((g == 2) ? c2[0] : c3[0]);                \
        ph[PH_WR][st] = f2bf(val * scale);   /* p-path: mul+cvt+write */ \
        s = NPprev + __logf(val) + e_cur;    /* off p-path */            \
        if (tid == 0) nmr[WSLOT] = s;        /* consumed at t+2 */       \
        NPprev = Dt;                                                     \
        BARRIER();                                                       \
    }

__global__ void __launch_bounds__(256, 1)
k_forward(const float* __restrict__ yp_all,
          const unsigned short* __restrict__ ETB,
          const float* __restrict__ path,
          float* __restrict__ out) {
    int b = blockIdx.x, tid = threadIdx.x;
    int w = tid >> 6;            // wave: owns states [64w, 64w+64)
    int i = tid & 63;            // lane
    int g = i >> 4;              // lane group 0..3
    const int st = (w << 6) + i; // this lane's state
    const float* yp = yp_all + (size_t)b * T_ * L_;

    // ---- stage B-fragments (32 x 16B) into physical a0..a127 ----
    {
        const uint32x4* etb4 = (const uint32x4*)ETB;
        int vbase = w * 2048 + i;
        STGF( 0,   0,  1,  2,  3)  STGF( 1,   4,  5,  6,  7)
        STGF( 2,   8,  9, 10, 11)  STGF( 3,  12, 13, 14, 15)
        STGF( 4,  16, 17, 18, 19)  STGF( 5,  20, 21, 22, 23)
        STGF( 6,  24, 25, 26, 27)  STGF( 7,  28, 29, 30, 31)
        STGF( 8,  32, 33, 34, 35)  STGF( 9,  36, 37, 38, 39)
        STGF(10,  40, 41, 42, 43)  STGF(11,  44, 45, 46, 47)
        STGF(12,  48, 49, 50, 51)  STGF(13,  52, 53, 54, 55)
        STGF(14,  56, 57, 58, 59)  STGF(15,  60, 61, 62, 63)
        STGF(16,  64, 65, 66, 67)  STGF(17,  68, 69, 70, 71)
        STGF(18,  72, 73, 74, 75)  STGF(19,  76, 77, 78, 79)
        STGF(20,  80, 81, 82, 83)  STGF(21,  84, 85, 86, 87)
        STGF(22,  88, 89, 90, 91)  STGF(23,  92, 93, 94, 95)
        STGF(24,  96, 97, 98, 99)  STGF(25, 100,101,102,103)
        STGF(26, 104,105,106,107)  STGF(27, 108,109,110,111)
        STGF(28, 112,113,114,115)  STGF(29, 116,117,118,119)
        STGF(30, 120,121,122,123)  STGF(31, 124,125,126,127)
    }

    __shared__ alignas(16) unsigned short ph[2][L_];  // p (bf16), dbuf
    __shared__ float red[8];
    __shared__ float nmr[4];                          // D ring, lag-2

    // ---- init: s0, exact max N0, p0 ----
    float s = yp[st];
    {
        float v = s;
#pragma unroll
        for (int off = 1; off < 64; off <<= 1) v = fmaxf(v, __shfl_xor(v, off, 64));
        if (i == 0) red[w] = v;
        __syncthreads();
        if (tid == 0) {
            float M = fmaxf(fmaxf(red[0], red[1]), fmaxf(red[2], red[3]));
            nmr[0] = M; nmr[1] = M; nmr[2] = M; nmr[3] = M;
        }
        __syncthreads();
    }
    float NPprev = nmr[0];                 // D_0 = N0
    ph[1][st] = f2bf(__expf(s - NPprev));  // p_0

    // emit regs: e0=E(1), e1=E(2), e2=E(3), e3=E(4)
    float e0 = yp[(size_t)1 * L_ + st];
    float e1 = yp[(size_t)2 * L_ + st];
    float e2 = yp[(size_t)3 * L_ + st];
    float e3 = yp[(size_t)4 * L_ + st];
    __syncthreads();   // p0 + nmr visible (one-time full drain is fine)

    // main loop: t = 1..508 in 4x bodies (t ≡ 1 mod 4)
    for (int t = 1; t < 509; t += 4) {
        STEP(t + 0, 1, 0, 3, 1, e0)
        STEP(t + 1, 0, 1, 0, 2, e1)
        STEP(t + 2, 1, 0, 1, 3, e2)
        STEP(t + 3, 0, 1, 2, 0, e3)
    }
    // peeled: t = 509, 510, 511
    STEP(509, 1, 0, 3, 1, e0)
    STEP(510, 0, 1, 0, 2, e1)
    STEP(511, 1, 0, 1, 3, e2)

    // ---- final logsumexp over states (all lanes hold unique st) ----
    {
        float v = s;
#pragma unroll
        for (int off = 1; off < 64; off <<= 1) v = fmaxf(v, __shfl_xor(v, off, 64));
        if (i == 0) red[w] = v;
    }
    __syncthreads();
    float M = fmaxf(fmaxf(red[0], red[1]), fmaxf(red[2], red[3]));
    float e = __expf(s - M);
#pragma unroll
    for (int off = 1; off < 64; off <<= 1) e += __shfl_xor(e, off, 64);
    if (i == 0) red[4 + w] = e;
    __syncthreads();
    if (tid == 0)
        out[b] = M + __logf((red[4] + red[5]) + (red[6] + red[7])) - path[b];
}

// ---------------------------------------------------------------------------
extern "C" void kernel_launch(void* const* d_in, const int* in_sizes, int n_in,
                              void* d_out, int out_size, void* d_ws, size_t ws_size,
                              hipStream_t stream) {
    const float* y_true = (const float*)d_in[0];
    const float* y_pre  = (const float*)d_in[1];
    const float* trans  = (const float*)d_in[2];
    float* out = (float*)d_out;

    char* ws = (char*)d_ws;
    unsigned short* ETB = (unsigned short*)ws;            // 128 KiB (frag order)
    int* labels = (int*)(ws + 131072);                    // 256 KiB
    float* path = (float*)(ws + 131072 + 262144);         // 512 B

    hipLaunchKernelGGL(k_exptrans, dim3(L_), dim3(L_), 0, stream, trans, ETB);
    hipLaunchKernelGGL(k_labels, dim3(B_ * T_ / 4), dim3(256), 0, stream, y_true, labels);
    hipLaunchKernelGGL(k_path, dim3(B_), dim3(256), 0, stream, y_pre, trans, labels, path);
    hipLaunchKernelGGL(k_forward, dim3(B_), dim3(256), 0, stream, y_pre, ETB, path, out);
}

// Round 24
// 238.808 us; speedup vs baseline: 1.0982x; 1.0029x over previous
//
#include <hip/hip_runtime.h>
#include <hip/hip_bf16.h>

#define B_ 128
#define T_ 512
#define L_ 256

typedef float f32x4 __attribute__((ext_vector_type(4)));
typedef unsigned uint32x4 __attribute__((ext_vector_type(4)));

__device__ __forceinline__ unsigned short f2bf(float x) {  // RNE f32->bf16
    unsigned u = __builtin_bit_cast(unsigned, x);
    return (unsigned short)((u + 0x7fff + ((u >> 16) & 1)) >> 16);
}

// Physical-AGPR staging (rounds 9-18-proven; regalloc cannot touch).
#define AW(n, v) asm volatile("v_accvgpr_write_b32 a" #n ", %0" :: "v"(v) : "a" #n)
#define STGF(F, A0, A1, A2, A3) { uint32x4 qq = etb4[vbase + F * 64]; \
    AW(A0, qq[0]); AW(A1, qq[1]); AW(A2, qq[2]); AW(A3, qq[3]); }

// MFMA with B operand in hard-coded physical AGPRs (gfx950 unified RF).
#define MFMA_AB(ACC, AF, LO, HI) \
    asm volatile("v_mfma_f32_16x16x32_bf16 %0, %1, a[" #LO ":" #HI "], %0" \
                 : "+v"(ACC) : "v"(AF))

// lgkmcnt-only barrier (no vmcnt drain).
#define BARRIER() asm volatile("s_waitcnt lgkmcnt(0)\n\ts_barrier" ::: "memory")

// ---------------------------------------------------------------------------
// Kernel A: ETB = bf16(exp(trans)) pre-packed in MFMA B-fragment order.
// (HW-verified by round-10 absmax 0.0)
// ---------------------------------------------------------------------------
__global__ __launch_bounds__(256) void k_exptrans(const float* __restrict__ trans,
                                                  unsigned short* __restrict__ ETB) {
    int l = blockIdx.x;          // 256 blocks = rows of trans
    int m = threadIdx.x;         // 256 threads = cols
    unsigned short v = f2bf(__expf(trans[l * L_ + m]));
    unsigned byte = (unsigned)((m >> 4) * 8 + (l >> 5)) * 1024u
                  + (unsigned)(((l >> 3) & 3) * 16 + (m & 15)) * 16u
                  + (unsigned)(((l >> 1) & 3)) * 4u + (unsigned)(l & 1) * 2u;
    *(unsigned short*)((char*)ETB + byte) = v;
}

// ---------------------------------------------------------------------------
// Kernel B: labels from one-hot y_true (one wave per row)
// ---------------------------------------------------------------------------
__global__ __launch_bounds__(256) void k_labels(const float* __restrict__ y_true,
                                                int* __restrict__ labels) {
    int wid = threadIdx.x >> 6, lane = threadIdx.x & 63;
    int r = blockIdx.x * 4 + wid;
    const float4* row = (const float4*)(y_true + (size_t)r * L_);
    float4 v = row[lane];
    int loc = -1;
    if (v.x > 0.5f) loc = lane * 4 + 0;
    if (v.y > 0.5f) loc = lane * 4 + 1;
    if (v.z > 0.5f) loc = lane * 4 + 2;
    if (v.w > 0.5f) loc = lane * 4 + 3;
    unsigned long long m = __ballot(loc >= 0);
    int src = __ffsll(m) - 1;
    int lab = __shfl(loc, src, 64);
    if (lane == 0) labels[r] = lab;
}

// ---------------------------------------------------------------------------
// Kernel C: path_score
// ---------------------------------------------------------------------------
__global__ __launch_bounds__(256) void k_path(const float* __restrict__ y_pre,
                                              const float* __restrict__ trans,
                                              const int* __restrict__ labels,
                                              float* __restrict__ path) {
    int b = blockIdx.x, tid = threadIdx.x;
    const int* lb = labels + b * T_;
    float acc = 0.f;
    for (int t = tid; t < T_; t += 256) {
        int l1 = lb[t];
        acc += y_pre[((size_t)b * T_ + t) * L_ + l1];
        if (t + 1 < T_) acc += trans[l1 * L_ + lb[t + 1]];
    }
#pragma unroll
    for (int off = 1; off < 64; off <<= 1) acc += __shfl_xor(acc, off, 64);
    __shared__ float red[4];
    int wid = tid >> 6, lane = tid & 63;
    if (lane == 0) red[wid] = acc;
    __syncthreads();
    if (tid == 0) path[b] = red[0] + red[1] + red[2] + red[3];
}

// ---------------------------------------------------------------------------
// Kernel D: forward recursion via MFMA — round-18 BEST-PASSING build,
// restored verbatim (239.5us, absmax 32). 4 waves, B in a0..a127, lag-2
// nmr ring, 4x-unrolled loop, emit issued at step top. Step = 1062cy:
// ~250cy MFMA-busy + ~110cy VALU + un-hidden serial latency at 1 wave/SIMD.
// All TLP attempts to hide the serial part (8-wave: r11/r13/r22/r23;
// fp8 K=128: r19-21) failed with undebuggable-in-this-loop errors.
// ---------------------------------------------------------------------------
#define MFMA32()                                                         \
        MFMA_AB(c0, af0,   0,   3); MFMA_AB(c1, af0,  32,  35);          \
        MFMA_AB(c2, af0,  64,  67); MFMA_AB(c3, af0,  96,  99);          \
        MFMA_AB(c0, af1,   4,   7); MFMA_AB(c1, af1,  36,  39);          \
        MFMA_AB(c2, af1,  68,  71); MFMA_AB(c3, af1, 100, 103);          \
        MFMA_AB(c0, af2,   8,  11); MFMA_AB(c1, af2,  40,  43);          \
        MFMA_AB(c2, af2,  72,  75); MFMA_AB(c3, af2, 104, 107);          \
        MFMA_AB(c0, af3,  12,  15); MFMA_AB(c1, af3,  44,  47);          \
        MFMA_AB(c2, af3,  76,  79); MFMA_AB(c3, af3, 108, 111);          \
        MFMA_AB(c0, af4,  16,  19); MFMA_AB(c1, af4,  48,  51);          \
        MFMA_AB(c2, af4,  80,  83); MFMA_AB(c3, af4, 112, 115);          \
        MFMA_AB(c0, af5,  20,  23); MFMA_AB(c1, af5,  52,  55);          \
        MFMA_AB(c2, af5,  84,  87); MFMA_AB(c3, af5, 116, 119);          \
        MFMA_AB(c0, af6,  24,  27); MFMA_AB(c1, af6,  56,  59);          \
        MFMA_AB(c2, af6,  88,  91); MFMA_AB(c3, af6, 120, 123);          \
        MFMA_AB(c0, af7,  28,  31); MFMA_AB(c1, af7,  60,  63);          \
        MFMA_AB(c2, af7,  92,  95); MFMA_AB(c3, af7, 124, 127);

#define STEP(TT, PH_RD, PH_WR, DSLOT, WSLOT, EREG)                       \
    {                                                                    \
        float e_cur = EREG;                  /* E(t), 4-step-old load */ \
        { int tp = (TT) + 4; if (tp > T_ - 1) tp = T_ - 1;               \
          EREG = yp[(size_t)tp * L_ + st]; } /* issue E(t+4) at TOP */   \
        float Dt = nmr[DSLOT];              /* s_{t-2}[0], 2 barriers old */ \
        float scale = __expf(NPprev + e_cur - Dt);  /* overlaps MFMA */  \
        const uint32x4* pA = (const uint32x4*)ph[PH_RD];                 \
        uint32x4 af0 = pA[g];      uint32x4 af1 = pA[g + 4];             \
        uint32x4 af2 = pA[g + 8];  uint32x4 af3 = pA[g + 12];            \
        uint32x4 af4 = pA[g + 16]; uint32x4 af5 = pA[g + 20];            \
        uint32x4 af6 = pA[g + 24]; uint32x4 af7 = pA[g + 28];            \
        f32x4 c0 = {0.f,0.f,0.f,0.f}, c1 = {0.f,0.f,0.f,0.f};            \
        f32x4 c2 = {0.f,0.f,0.f,0.f}, c3 = {0.f,0.f,0.f,0.f};            \
        MFMA32()                                                         \
        float val = (g < 2) ? ((g == 0) ? c0[0] : c1[0])                 \
                            : ((g == 2) ? c2[0] : c3[0]);                \
        ph[PH_WR][st] = f2bf(val * scale);   /* p-path: mul+cvt+write */ \
        s = NPprev + __logf(val) + e_cur;    /* off p-path */            \
        if (tid == 0) nmr[WSLOT] = s;        /* consumed at t+2 */       \
        NPprev = Dt;                                                     \
        BARRIER();                                                       \
    }

__global__ void __launch_bounds__(256, 1)
k_forward(const float* __restrict__ yp_all,
          const unsigned short* __restrict__ ETB,
          const float* __restrict__ path,
          float* __restrict__ out) {
    int b = blockIdx.x, tid = threadIdx.x;
    int w = tid >> 6;            // wave: owns states [64w, 64w+64)
    int i = tid & 63;            // lane
    int g = i >> 4;              // lane group 0..3
    const int st = (w << 6) + i; // this lane's state
    const float* yp = yp_all + (size_t)b * T_ * L_;

    // ---- stage B-fragments (32 x 16B) into physical a0..a127 ----
    {
        const uint32x4* etb4 = (const uint32x4*)ETB;
        int vbase = w * 2048 + i;
        STGF( 0,   0,  1,  2,  3)  STGF( 1,   4,  5,  6,  7)
        STGF( 2,   8,  9, 10, 11)  STGF( 3,  12, 13, 14, 15)
        STGF( 4,  16, 17, 18, 19)  STGF( 5,  20, 21, 22, 23)
        STGF( 6,  24, 25, 26, 27)  STGF( 7,  28, 29, 30, 31)
        STGF( 8,  32, 33, 34, 35)  STGF( 9,  36, 37, 38, 39)
        STGF(10,  40, 41, 42, 43)  STGF(11,  44, 45, 46, 47)
        STGF(12,  48, 49, 50, 51)  STGF(13,  52, 53, 54, 55)
        STGF(14,  56, 57, 58, 59)  STGF(15,  60, 61, 62, 63)
        STGF(16,  64, 65, 66, 67)  STGF(17,  68, 69, 70, 71)
        STGF(18,  72, 73, 74, 75)  STGF(19,  76, 77, 78, 79)
        STGF(20,  80, 81, 82, 83)  STGF(21,  84, 85, 86, 87)
        STGF(22,  88, 89, 90, 91)  STGF(23,  92, 93, 94, 95)
        STGF(24,  96, 97, 98, 99)  STGF(25, 100,101,102,103)
        STGF(26, 104,105,106,107)  STGF(27, 108,109,110,111)
        STGF(28, 112,113,114,115)  STGF(29, 116,117,118,119)
        STGF(30, 120,121,122,123)  STGF(31, 124,125,126,127)
    }

    __shared__ alignas(16) unsigned short ph[2][L_];  // p (bf16), dbuf
    __shared__ float red[8];
    __shared__ float nmr[4];                          // D ring, lag-2

    // ---- init: s0, exact max N0, p0 ----
    float s = yp[st];
    {
        float v = s;
#pragma unroll
        for (int off = 1; off < 64; off <<= 1) v = fmaxf(v, __shfl_xor(v, off, 64));
        if (i == 0) red[w] = v;
        __syncthreads();
        if (tid == 0) {
            float M = fmaxf(fmaxf(red[0], red[1]), fmaxf(red[2], red[3]));
            nmr[0] = M; nmr[1] = M; nmr[2] = M; nmr[3] = M;
        }
        __syncthreads();
    }
    float NPprev = nmr[0];                 // D_0 = N0
    ph[1][st] = f2bf(__expf(s - NPprev));  // p_0

    // emit regs: e0=E(1), e1=E(2), e2=E(3), e3=E(4)
    float e0 = yp[(size_t)1 * L_ + st];
    float e1 = yp[(size_t)2 * L_ + st];
    float e2 = yp[(size_t)3 * L_ + st];
    float e3 = yp[(size_t)4 * L_ + st];
    __syncthreads();   // p0 + nmr visible (one-time full drain is fine)

    // main loop: t = 1..508 in 4x bodies (t ≡ 1 mod 4)
    for (int t = 1; t < 509; t += 4) {
        STEP(t + 0, 1, 0, 3, 1, e0)
        STEP(t + 1, 0, 1, 0, 2, e1)
        STEP(t + 2, 1, 0, 1, 3, e2)
        STEP(t + 3, 0, 1, 2, 0, e3)
    }
    // peeled: t = 509, 510, 511
    STEP(509, 1, 0, 3, 1, e0)
    STEP(510, 0, 1, 0, 2, e1)
    STEP(511, 1, 0, 1, 3, e2)

    // ---- final logsumexp over states (all lanes hold unique st) ----
    {
        float v = s;
#pragma unroll
        for (int off = 1; off < 64; off <<= 1) v = fmaxf(v, __shfl_xor(v, off, 64));
        if (i == 0) red[w] = v;
    }
    __syncthreads();
    float M = fmaxf(fmaxf(red[0], red[1]), fmaxf(red[2], red[3]));
    float e = __expf(s - M);
#pragma unroll
    for (int off = 1; off < 64; off <<= 1) e += __shfl_xor(e, off, 64);
    if (i == 0) red[4 + w] = e;
    __syncthreads();
    if (tid == 0)
        out[b] = M + __logf((red[4] + red[5]) + (red[6] + red[7])) - path[b];
}

// ---------------------------------------------------------------------------
extern "C" void kernel_launch(void* const* d_in, const int* in_sizes, int n_in,
                              void* d_out, int out_size, void* d_ws, size_t ws_size,
                              hipStream_t stream) {
    const float* y_true = (const float*)d_in[0];
    const float* y_pre  = (const float*)d_in[1];
    const float* trans  = (const float*)d_in[2];
    float* out = (float*)d_out;

    char* ws = (char*)d_ws;
    unsigned short* ETB = (unsigned short*)ws;            // 128 KiB (frag order)
    int* labels = (int*)(ws + 131072);                    // 256 KiB
    float* path = (float*)(ws + 131072 + 262144);         // 512 B

    hipLaunchKernelGGL(k_exptrans, dim3(L_), dim3(L_), 0, stream, trans, ETB);
    hipLaunchKernelGGL(k_labels, dim3(B_ * T_ / 4), dim3(256), 0, stream, y_true, labels);
    hipLaunchKernelGGL(k_path, dim3(B_), dim3(256), 0, stream, y_pre, trans, labels, path);
    hipLaunchKernelGGL(k_forward, dim3(B_), dim3(256), 0, stream, y_pre, ETB, path, out);
}